// Round 2
// baseline (858.957 us; speedup 1.0000x reference)
//
#include <hip/hip_runtime.h>

#define Hdim 1024
#define Bdim 32
#define Sdim 2048

typedef __attribute__((ext_vector_type(8))) __bf16 bf16x8;
typedef __attribute__((ext_vector_type(4))) float f32x4;

#define GLOAD_LDS16(gp, lp)                                                              \
  __builtin_amdgcn_global_load_lds(                                                     \
      (const __attribute__((address_space(1))) unsigned int*)(gp),                      \
      (__attribute__((address_space(3))) unsigned int*)(lp), 16, 0, 0)

// ---------------------------------------------------------------------------
// key (S*B x H fp32, row-major) -> bf16, same layout. Pure streaming pass.
__global__ __launch_bounds__(256) void convert_key_kernel(const float* __restrict__ key,
                                                          __bf16* __restrict__ bkey) {
  size_t idx = (size_t)blockIdx.x * 256 + threadIdx.x;  // 8 elements per thread
  const float4* src = (const float4*)(key + idx * 8);
  float4 f0 = src[0], f1 = src[1];
  bf16x8 t;
  t[0] = (__bf16)f0.x; t[1] = (__bf16)f0.y; t[2] = (__bf16)f0.z; t[3] = (__bf16)f0.w;
  t[4] = (__bf16)f1.x; t[5] = (__bf16)f1.y; t[6] = (__bf16)f1.z; t[7] = (__bf16)f1.w;
  *(bf16x8*)(bkey + idx * 8) = t;
}

// ---------------------------------------------------------------------------
// Ua (H x H fp32, row-major k-major) -> bf16 in [ntile][k8][n][8] order so the
// GEMM's B fragments are k-contiguous per lane (direct-to-register loads).
__global__ __launch_bounds__(256) void convert_ua_kernel(const float* __restrict__ Ua,
                                                         __bf16* __restrict__ ubt) {
  int du = blockIdx.x * 256 + threadIdx.x;  // 0..131071 (16B units)
  int n  = du & 127;
  int k8 = (du >> 7) & 127;
  int nt = du >> 14;
  int ng = nt * 128 + n;
  bf16x8 t;
#pragma unroll
  for (int j = 0; j < 8; ++j)
    t[j] = (__bf16)Ua[(k8 * 8 + j) * Hdim + ng];
  *(bf16x8*)(ubt + (size_t)du * 8) = t;
}

// ---------------------------------------------------------------------------
// qc[b,h] = query[b] @ Wa_w + Wa_b + Ua_b   (fp32, tiny: 67 MFLOP)
__global__ __launch_bounds__(256) void qc_kernel(const float* __restrict__ q,
                                                 const float* __restrict__ Wa,
                                                 const float* __restrict__ Wab,
                                                 const float* __restrict__ Uab,
                                                 float* __restrict__ qc) {
  int b = blockIdx.y;
  int h = blockIdx.x * 256 + threadIdx.x;
  float acc = Wab[h] + Uab[h];
  const float* qr = q + b * Hdim;
#pragma unroll 16
  for (int i = 0; i < Hdim; ++i)
    acc = fmaf(qr[i], Wa[i * Hdim + h], acc);
  qc[b * Hdim + h] = acc;
}

// ---------------------------------------------------------------------------
// Fused score GEMM, bf16 A path — LDS-FREE / BARRIER-FREE main loop.
// A fragments load directly from row-major bkey (k-contiguous 16B per lane;
// each wave instruction touches 16 fully-consumed 64B lines — same line count
// as a coalesced load). B fragments load from ubt's [nt][k8][n][8] layout
// (2 MiB, L2-resident; all 8 nt-blocks of one mt share an XCD).
// Explicit 2-deep register pipeline (named sets aA/bA vs aB/bB, static
// indexing) lets loads run ~1.5 K-steps ahead of their MFMA use; no wave
// ever drains vmcnt at a barrier.
// part is written TRANSPOSED: part[b][s][nt] so softmax reads coalesced.
__global__ __launch_bounds__(256) void gemm_scores_bf16_kernel(const __bf16* __restrict__ bkey,
                                                               const __bf16* __restrict__ ubt,
                                                               const float* __restrict__ qc,
                                                               const float* __restrict__ va,
                                                               float* __restrict__ part) {
  __shared__ float qcs[4096];   // epilogue only
  __shared__ float red[256];

  const int tid  = threadIdx.x;
  const int w    = tid >> 6;
  const int lane = tid & 63;
  const int quad = lane >> 4;
  const int l16  = lane & 15;

  const int l   = blockIdx.x;
  const int xcd = l & 7;
  const int i2  = l >> 3;
  const int mt  = xcd * 64 + (i2 >> 3);  // 0..511  (same XCD for all 8 nt of one mt)
  const int nt  = i2 & 7;                // 0..7

  const int r0 = mt * 128;
  const int n0 = nt * 128;
  const int wm = (w & 1) * 64;
  const int wn = (w >> 1) * 64;

  // Per-lane fragment base pointers.
  // afr[i] @ kc  = Abase + i*16*Hdim + kc          (element (row, k))
  // bfr[j] @ kc  = Bbase + kc*128 + j*128          (ubt unit stride 8 bf16)
  const __bf16* Abase = bkey + ((size_t)(r0 + wm + l16)) * Hdim + quad * 8;
  const __bf16* Bbase = ubt + ((size_t)nt * 16384 + (size_t)quad * 128 + wn + l16) * 8;

  f32x4 acc[4][4] = {};
  bf16x8 aA[4], bA[4], aB[4], bB[4];

  // prologue: fragments for k=0
#pragma unroll
  for (int i = 0; i < 4; ++i) aA[i] = *(const bf16x8*)(Abase + (size_t)i * 16 * Hdim);
#pragma unroll
  for (int j = 0; j < 4; ++j) bA[j] = *(const bf16x8*)(Bbase + (size_t)j * 128);

#pragma unroll
  for (int s = 0; s < 16; ++s) {
    const int k0 = s * 64;
    // load half-step k0+32 into the B register set
#pragma unroll
    for (int i = 0; i < 4; ++i)
      aB[i] = *(const bf16x8*)(Abase + (size_t)i * 16 * Hdim + k0 + 32);
#pragma unroll
    for (int j = 0; j < 4; ++j)
      bB[j] = *(const bf16x8*)(Bbase + (size_t)(k0 + 32) * 128 + (size_t)j * 128);

    // MFMA half-step k0 (A register set)
#pragma unroll
    for (int i = 0; i < 4; ++i)
#pragma unroll
      for (int j = 0; j < 4; ++j)
        acc[i][j] = __builtin_amdgcn_mfma_f32_16x16x32_bf16(aA[i], bA[j], acc[i][j], 0, 0, 0);

    // load half-step k0+64 into the A register set (compile-time guard)
    if (s < 15) {
      const int k1 = k0 + 64;
#pragma unroll
      for (int i = 0; i < 4; ++i)
        aA[i] = *(const bf16x8*)(Abase + (size_t)i * 16 * Hdim + k1);
#pragma unroll
      for (int j = 0; j < 4; ++j)
        bA[j] = *(const bf16x8*)(Bbase + (size_t)k1 * 128 + (size_t)j * 128);
    }

    // MFMA half-step k0+32 (B register set)
#pragma unroll
    for (int i = 0; i < 4; ++i)
#pragma unroll
      for (int j = 0; j < 4; ++j)
        acc[i][j] = __builtin_amdgcn_mfma_f32_16x16x32_bf16(aB[i], bB[j], acc[i][j], 0, 0, 0);
  }

  // stage qc tile (32 b-rows x 128 n-cols) into LDS
#pragma unroll
  for (int it = 0; it < 16; ++it) {
    int u = it * 256 + tid;
    qcs[u] = qc[(u >> 7) * Hdim + n0 + (u & 127)];
  }
  __syncthreads();

  float vav[4];
#pragma unroll
  for (int j = 0; j < 4; ++j) vav[j] = va[n0 + wn + j * 16 + l16];

  // C/D layout (m89): col = lane&15 (n), row = quad*4 + reg (m)
#pragma unroll
  for (int i = 0; i < 4; ++i) {
#pragma unroll
    for (int rg = 0; rg < 4; ++rg) {
      int b = (i & 1) * 16 + quad * 4 + rg;
      float sum = 0.f;
#pragma unroll
      for (int j = 0; j < 4; ++j) {
        float v = acc[i][j][rg] + qcs[b * 128 + wn + j * 16 + l16];
        v = fminf(fmaxf(v, -15.f), 15.f);
        float e = __expf(2.f * v);
        sum += (e - 1.f) * __builtin_amdgcn_rcpf(e + 1.f) * vav[j];
      }
#pragma unroll
      for (int off = 1; off < 16; off <<= 1)
        sum += __shfl_xor(sum, off, 64);
      if (l16 == 0)
        red[(wm + i * 16 + quad * 4 + rg) * 2 + (w >> 1)] = sum;
    }
  }
  __syncthreads();
  if (tid < 128) {
    int row = r0 + tid;              // row = s*32 + b
    int bb = row & 31, ss = row >> 5;
    part[((size_t)bb * Sdim + ss) * 8 + nt] = red[tid * 2] + red[tid * 2 + 1];
  }
}

// ---------------------------------------------------------------------------
// Fallback fp32-A GEMM (known-good) in case ws can't hold bkey.
__global__ __launch_bounds__(256) void gemm_scores_kernel(const float* __restrict__ key,
                                                          const __bf16* __restrict__ ubt,
                                                          const float* __restrict__ qc,
                                                          const float* __restrict__ va,
                                                          float* __restrict__ part) {
  __shared__ __align__(16) float AsQ[4096];
  __shared__ __align__(16) __bf16 Bs[4096];
  __shared__ float red[256];

  const int tid  = threadIdx.x;
  const int w    = tid >> 6;
  const int lane = tid & 63;
  const int quad = lane >> 4;
  const int l16  = lane & 15;
  const int l   = blockIdx.x;
  const int xcd = l & 7;
  const int i2  = l >> 3;
  const int mt  = xcd * 64 + (i2 >> 3);
  const int nt  = i2 & 7;
  const int r0 = mt * 128;
  const int n0 = nt * 128;
  const int wm = (w & 1) * 64;
  const int wn = (w >> 1) * 64;

  f32x4 acc[4][4] = {};

  for (int kc = 0; kc < Hdim; kc += 32) {
#pragma unroll
    for (int it = 0; it < 4; ++it) {
      int u  = it * 256 + tid;
      int k4 = u >> 7, row = u & 127;
      GLOAD_LDS16(key + (size_t)(r0 + row) * Hdim + kc + k4 * 4, AsQ + u * 4);
    }
#pragma unroll
    for (int it = 0; it < 2; ++it) {
      int u = it * 256 + tid;
      GLOAD_LDS16(ubt + ((size_t)nt * 16384 + (kc >> 3) * 128 + u) * 8, Bs + u * 8);
    }
    __syncthreads();

    bf16x8 bfr[4];
#pragma unroll
    for (int j = 0; j < 4; ++j)
      bfr[j] = *(const bf16x8*)&Bs[(quad * 128 + wn + j * 16 + l16) * 8];

    bf16x8 afr[4];
#pragma unroll
    for (int i = 0; i < 4; ++i) {
      int ml = wm + i * 16 + l16;
      float4 f0 = *(const float4*)&AsQ[((quad * 2) * 128 + ml) * 4];
      float4 f1 = *(const float4*)&AsQ[((quad * 2 + 1) * 128 + ml) * 4];
      bf16x8 a;
      a[0] = (__bf16)f0.x; a[1] = (__bf16)f0.y; a[2] = (__bf16)f0.z; a[3] = (__bf16)f0.w;
      a[4] = (__bf16)f1.x; a[5] = (__bf16)f1.y; a[6] = (__bf16)f1.z; a[7] = (__bf16)f1.w;
      afr[i] = a;
    }

#pragma unroll
    for (int i = 0; i < 4; ++i)
#pragma unroll
      for (int j = 0; j < 4; ++j)
        acc[i][j] = __builtin_amdgcn_mfma_f32_16x16x32_bf16(afr[i], bfr[j], acc[i][j], 0, 0, 0);

    __syncthreads();
  }

#pragma unroll
  for (int it = 0; it < 16; ++it) {
    int u = it * 256 + tid;
    AsQ[u] = qc[(u >> 7) * Hdim + n0 + (u & 127)];
  }
  __syncthreads();

  float vav[4];
#pragma unroll
  for (int j = 0; j < 4; ++j) vav[j] = va[n0 + wn + j * 16 + l16];

#pragma unroll
  for (int i = 0; i < 4; ++i) {
#pragma unroll
    for (int rg = 0; rg < 4; ++rg) {
      int b = (i & 1) * 16 + quad * 4 + rg;
      float sum = 0.f;
#pragma unroll
      for (int j = 0; j < 4; ++j) {
        float v = acc[i][j][rg] + AsQ[b * 128 + wn + j * 16 + l16];
        v = fminf(fmaxf(v, -15.f), 15.f);
        float e = __expf(2.f * v);
        sum += (e - 1.f) * __builtin_amdgcn_rcpf(e + 1.f) * vav[j];
      }
#pragma unroll
      for (int off = 1; off < 16; off <<= 1)
        sum += __shfl_xor(sum, off, 64);
      if (l16 == 0)
        red[(wm + i * 16 + quad * 4 + rg) * 2 + (w >> 1)] = sum;
    }
  }
  __syncthreads();
  if (tid < 128) {
    int row = r0 + tid;
    int bb = row & 31, ss = row >> 5;
    part[((size_t)bb * Sdim + ss) * 8 + nt] = red[tid * 2] + red[tid * 2 + 1];
  }
}

// ---------------------------------------------------------------------------
// part layout: [b][s][8 nt-partials]; block b reads 64 KiB fully coalesced.
__global__ __launch_bounds__(256) void softmax_kernel(const float* __restrict__ part,
                                                      float* __restrict__ dout) {
  int b = blockIdx.x, t = threadIdx.x;
  int w = t >> 6, lane = t & 63;
  __shared__ float red1[4], red2[4];
  float sc[8];
  float m = -1e30f;
#pragma unroll
  for (int c = 0; c < 8; ++c) {
    int s = c * 256 + t;
    const float4* p = (const float4*)&part[((size_t)b * Sdim + s) * 8];
    float4 p0 = p[0], p1 = p[1];
    float v = ((p0.x + p0.y) + (p0.z + p0.w)) + ((p1.x + p1.y) + (p1.z + p1.w));
    sc[c] = v;
    m = fmaxf(m, v);
  }
#pragma unroll
  for (int off = 1; off < 64; off <<= 1) m = fmaxf(m, __shfl_xor(m, off, 64));
  if (lane == 0) red1[w] = m;
  __syncthreads();
  m = fmaxf(fmaxf(red1[0], red1[1]), fmaxf(red1[2], red1[3]));
  float sum = 0.f;
#pragma unroll
  for (int c = 0; c < 8; ++c) { sc[c] = __expf(sc[c] - m); sum += sc[c]; }
#pragma unroll
  for (int off = 1; off < 64; off <<= 1) sum += __shfl_xor(sum, off, 64);
  if (lane == 0) red2[w] = sum;
  __syncthreads();
  float inv = 1.f / (red2[0] + red2[1] + red2[2] + red2[3]);
#pragma unroll
  for (int c = 0; c < 8; ++c)
    dout[32768 + b * 2048 + c * 256 + t] = sc[c] * inv;
}

// ---------------------------------------------------------------------------
__global__ __launch_bounds__(256) void ctx_part_kernel(const float* __restrict__ key,
                                                       const float* __restrict__ dout,
                                                       float* __restrict__ cpart) {
  int sc = blockIdx.x;
  int b  = blockIdx.y;
  int t  = threadIdx.x;
  float4 acc = make_float4(0.f, 0.f, 0.f, 0.f);
  int s0 = sc * 64;
#pragma unroll 8
  for (int s = s0; s < s0 + 64; ++s) {
    float wgt = dout[32768 + b * 2048 + s];
    float4 k4 = *(const float4*)&key[((size_t)(s * 32 + b) << 10) + t * 4];
    acc.x = fmaf(wgt, k4.x, acc.x);
    acc.y = fmaf(wgt, k4.y, acc.y);
    acc.z = fmaf(wgt, k4.z, acc.z);
    acc.w = fmaf(wgt, k4.w, acc.w);
  }
  *(float4*)&cpart[((size_t)(sc * 32 + b) << 10) + t * 4] = acc;
}

__global__ __launch_bounds__(256) void ctx_reduce_kernel(const float* __restrict__ cpart,
                                                         float* __restrict__ dout) {
  int o = blockIdx.x * 256 + threadIdx.x;
  int b = o >> 10, h = o & 1023;
  float s = 0.f;
#pragma unroll
  for (int sc = 0; sc < 32; ++sc)
    s += cpart[((size_t)(sc * 32 + b) << 10) + h];
  dout[o] = s;
}

// ---------------------------------------------------------------------------
extern "C" void kernel_launch(void* const* d_in, const int* in_sizes, int n_in,
                              void* d_out, int out_size, void* d_ws, size_t ws_size,
                              hipStream_t stream) {
  const float* q   = (const float*)d_in[0];
  const float* key = (const float*)d_in[1];
  const float* Waw = (const float*)d_in[2];
  const float* Wab = (const float*)d_in[3];
  const float* Uaw = (const float*)d_in[4];
  const float* Uab = (const float*)d_in[5];
  const float* vaw = (const float*)d_in[6];
  float* out = (float*)d_out;  // [0,32768): context ; [32768,98304): weights

  char* ws = (char*)d_ws;
  float*  qc    = (float*)(ws);                                 // 128 KiB
  __bf16* ubt   = (__bf16*)(ws + 131072);                       // 2 MiB
  float*  part  = (float*)(ws + 131072 + 2097152);              // 2 MiB
  float*  cpart = (float*)(ws + 131072 + 2097152 + 2097152);    // 4 MiB
  __bf16* bkey  = (__bf16*)(ws + 131072 + 2097152 + 2097152 + 4194304);  // 128 MiB
  const size_t need = 131072ull + 2097152 + 2097152 + 4194304 + 134217728;

  convert_ua_kernel<<<512, 256, 0, stream>>>(Uaw, ubt);
  qc_kernel<<<dim3(4, 32), 256, 0, stream>>>(q, Waw, Wab, Uab, qc);
  if (ws_size >= need) {
    convert_key_kernel<<<32768, 256, 0, stream>>>(key, bkey);
    gemm_scores_bf16_kernel<<<4096, 256, 0, stream>>>(bkey, ubt, qc, vaw, part);
  } else {
    gemm_scores_kernel<<<4096, 256, 0, stream>>>(key, ubt, qc, vaw, part);
  }
  softmax_kernel<<<32, 256, 0, stream>>>(part, out);
  ctx_part_kernel<<<dim3(32, 32), 256, 0, stream>>>(key, out, cpart);
  ctx_reduce_kernel<<<128, 256, 0, stream>>>(cpart, out);
}

// Round 3
// 681.670 us; speedup vs baseline: 1.2601x; 1.2601x over previous
//
#include <hip/hip_runtime.h>

#define Hdim 1024
#define Bdim 32
#define Sdim 2048

typedef __attribute__((ext_vector_type(8))) __bf16 bf16x8;
typedef __attribute__((ext_vector_type(4))) __bf16 bf16x4;
typedef __attribute__((ext_vector_type(4))) float f32x4;

#define GLOAD_LDS16(gp, lp)                                                              \
  __builtin_amdgcn_global_load_lds(                                                     \
      (const __attribute__((address_space(1))) unsigned int*)(gp),                      \
      (__attribute__((address_space(3))) unsigned int*)(lp), 16, 0, 0)

// ---------------------------------------------------------------------------
// key (S*B x H fp32, row-major) -> bf16, same layout. Block-strided so lanes
// read/write consecutive addresses (fully coalesced both sides).
__global__ __launch_bounds__(256) void convert_key_kernel(const float* __restrict__ key,
                                                          __bf16* __restrict__ bkey) {
  size_t base = (size_t)blockIdx.x * 512 + threadIdx.x;  // float4-unit index
  const float4* src = (const float4*)key;
  float4 f0 = src[base];
  float4 f1 = src[base + 256];
  bf16x4 a, b;
  a[0] = (__bf16)f0.x; a[1] = (__bf16)f0.y; a[2] = (__bf16)f0.z; a[3] = (__bf16)f0.w;
  b[0] = (__bf16)f1.x; b[1] = (__bf16)f1.y; b[2] = (__bf16)f1.z; b[3] = (__bf16)f1.w;
  bf16x4* dst = (bf16x4*)bkey;
  dst[base] = a;
  dst[base + 256] = b;
}

// ---------------------------------------------------------------------------
// Ua (H x H fp32, row-major k-major) -> bf16 in [ntile][k8][n][8] order so the
// GEMM's B staging is fully contiguous per K-chunk (8 KiB per chunk per ntile).
__global__ __launch_bounds__(256) void convert_ua_kernel(const float* __restrict__ Ua,
                                                         __bf16* __restrict__ ubt) {
  int du = blockIdx.x * 256 + threadIdx.x;  // 0..131071 (16B units)
  int n  = du & 127;
  int k8 = (du >> 7) & 127;
  int nt = du >> 14;
  int ng = nt * 128 + n;
  bf16x8 t;
#pragma unroll
  for (int j = 0; j < 8; ++j)
    t[j] = (__bf16)Ua[(k8 * 8 + j) * Hdim + ng];
  *(bf16x8*)(ubt + (size_t)du * 8) = t;
}

// ---------------------------------------------------------------------------
// qc[b,h] = query[b] @ Wa_w + Wa_b + Ua_b   (fp32, tiny: 67 MFLOP)
__global__ __launch_bounds__(256) void qc_kernel(const float* __restrict__ q,
                                                 const float* __restrict__ Wa,
                                                 const float* __restrict__ Wab,
                                                 const float* __restrict__ Uab,
                                                 float* __restrict__ qc) {
  int b = blockIdx.y;
  int h = blockIdx.x * 256 + threadIdx.x;
  float acc = Wab[h] + Uab[h];
  const float* qr = q + b * Hdim;
#pragma unroll 16
  for (int i = 0; i < Hdim; ++i)
    acc = fmaf(qr[i], Wa[i * Hdim + h], acc);
  qc[b * Hdim + h] = acc;
}

// ---------------------------------------------------------------------------
// Fused score GEMM, bf16 A path. 128x128 tile, BK=32, double-buffered LDS,
// prefetch-before-compute, ONE barrier per K-step. __launch_bounds__(256,4)
// targets <=128 unified VGPRs (64 acc + ~60 arch) -> 4 waves/SIMD for
// latency hiding (was 144 regs -> 3 waves/SIMD). Staging addresses are two
// incremented base pointers (cuts address-calc VGPRs).
// part is written TRANSPOSED: part[b][s][nt] so softmax reads coalesced.
__global__ __launch_bounds__(256, 4) void gemm_scores_bf16_kernel(const __bf16* __restrict__ bkey,
                                                                  const __bf16* __restrict__ ubt,
                                                                  const float* __restrict__ qc,
                                                                  const float* __restrict__ va,
                                                                  float* __restrict__ part) {
  // [buf][0..4095] = A tile ([k8][row][8]), [buf][4096..8191] = B tile ([k8][n][8])
  __shared__ __align__(16) __bf16 AB[2][8192];  // 32 KiB; epilogue reuses AB[0] as float[4096]
  __shared__ float red[256];

  const int tid  = threadIdx.x;
  const int w    = tid >> 6;
  const int lane = tid & 63;
  const int quad = lane >> 4;
  const int l16  = lane & 15;

  const int l   = blockIdx.x;
  const int xcd = l & 7;
  const int i2  = l >> 3;
  const int mt  = xcd * 64 + (i2 >> 3);  // 0..511  (same XCD for all 8 nt of one mt)
  const int nt  = i2 & 7;                // 0..7

  const int r0 = mt * 128;
  const int n0 = nt * 128;
  const int wm = (w & 1) * 64;
  const int wn = (w >> 1) * 64;

  // staging source pointers (advance per K-step)
  const __bf16* aSrc = bkey + (size_t)(r0 + (tid & 127)) * Hdim + (tid >> 7) * 8;
  const __bf16* bSrc = ubt + ((size_t)nt * 16384 + tid) * 8;

  f32x4 acc[4][4] = {};

  // ---- prologue: stage tile kc=0 into buf 0
  GLOAD_LDS16(aSrc,        &AB[0][tid * 8]);
  GLOAD_LDS16(aSrc + 16,   &AB[0][(tid + 256) * 8]);
  GLOAD_LDS16(bSrc,        &AB[0][4096 + tid * 8]);
  GLOAD_LDS16(bSrc + 2048, &AB[0][4096 + (tid + 256) * 8]);
  aSrc += 32;
  bSrc += 4096;
  __syncthreads();  // implicit vmcnt(0): tile 0 resident

  int cur = 0;
  for (int kc = 0; kc < Hdim; kc += 32) {
    // ---- prefetch next tile into buf cur^1 (issued before compute)
    if (kc + 32 < Hdim) {
      __bf16* nb = AB[cur ^ 1];
      GLOAD_LDS16(aSrc,        nb + tid * 8);
      GLOAD_LDS16(aSrc + 16,   nb + (tid + 256) * 8);
      GLOAD_LDS16(bSrc,        nb + 4096 + tid * 8);
      GLOAD_LDS16(bSrc + 2048, nb + 4096 + (tid + 256) * 8);
      aSrc += 32;
      bSrc += 4096;
    }

    // ---- compute current tile
    const __bf16* As = AB[cur];
    const __bf16* Bs = AB[cur] + 4096;
    bf16x8 afr[4], bfr[4];
#pragma unroll
    for (int i = 0; i < 4; ++i)
      afr[i] = *(const bf16x8*)&As[(quad * 128 + wm + i * 16 + l16) * 8];
#pragma unroll
    for (int j = 0; j < 4; ++j)
      bfr[j] = *(const bf16x8*)&Bs[(quad * 128 + wn + j * 16 + l16) * 8];

#pragma unroll
    for (int i = 0; i < 4; ++i)
#pragma unroll
      for (int j = 0; j < 4; ++j)
        acc[i][j] = __builtin_amdgcn_mfma_f32_16x16x32_bf16(afr[i], bfr[j], acc[i][j], 0, 0, 0);

    // one barrier per K-step: implicit vmcnt(0) waits prefetch, lgkmcnt(0)
    // guarantees this buffer's ds_reads are done before next-iter overwrite.
    __syncthreads();
    cur ^= 1;
  }

  // stage qc tile (32 b-rows x 128 n-cols) into LDS (reuse AB[0] as float[4096])
  float* qcs = (float*)AB[0];
#pragma unroll
  for (int it = 0; it < 16; ++it) {
    int u = it * 256 + tid;
    qcs[u] = qc[(u >> 7) * Hdim + n0 + (u & 127)];
  }
  __syncthreads();

  float vav[4];
#pragma unroll
  for (int j = 0; j < 4; ++j) vav[j] = va[n0 + wn + j * 16 + l16];

  // C/D layout (m89): col = lane&15 (n), row = quad*4 + reg (m)
#pragma unroll
  for (int i = 0; i < 4; ++i) {
#pragma unroll
    for (int rg = 0; rg < 4; ++rg) {
      int b = (i & 1) * 16 + quad * 4 + rg;
      float sum = 0.f;
#pragma unroll
      for (int j = 0; j < 4; ++j) {
        float v = acc[i][j][rg] + qcs[b * 128 + wn + j * 16 + l16];
        v = fminf(fmaxf(v, -15.f), 15.f);
        float e = __expf(2.f * v);
        sum += (e - 1.f) * __builtin_amdgcn_rcpf(e + 1.f) * vav[j];
      }
#pragma unroll
      for (int off = 1; off < 16; off <<= 1)
        sum += __shfl_xor(sum, off, 64);
      if (l16 == 0)
        red[(wm + i * 16 + quad * 4 + rg) * 2 + (w >> 1)] = sum;
    }
  }
  __syncthreads();
  if (tid < 128) {
    int row = r0 + tid;              // row = s*32 + b
    int bb = row & 31, ss = row >> 5;
    part[((size_t)bb * Sdim + ss) * 8 + nt] = red[tid * 2] + red[tid * 2 + 1];
  }
}

// ---------------------------------------------------------------------------
// Fallback fp32-A GEMM (known-good) in case ws can't hold bkey.
__global__ __launch_bounds__(256) void gemm_scores_kernel(const float* __restrict__ key,
                                                          const __bf16* __restrict__ ubt,
                                                          const float* __restrict__ qc,
                                                          const float* __restrict__ va,
                                                          float* __restrict__ part) {
  __shared__ __align__(16) float AsQ[4096];
  __shared__ __align__(16) __bf16 Bs[4096];
  __shared__ float red[256];

  const int tid  = threadIdx.x;
  const int w    = tid >> 6;
  const int lane = tid & 63;
  const int quad = lane >> 4;
  const int l16  = lane & 15;
  const int l   = blockIdx.x;
  const int xcd = l & 7;
  const int i2  = l >> 3;
  const int mt  = xcd * 64 + (i2 >> 3);
  const int nt  = i2 & 7;
  const int r0 = mt * 128;
  const int n0 = nt * 128;
  const int wm = (w & 1) * 64;
  const int wn = (w >> 1) * 64;

  f32x4 acc[4][4] = {};

  for (int kc = 0; kc < Hdim; kc += 32) {
#pragma unroll
    for (int it = 0; it < 4; ++it) {
      int u  = it * 256 + tid;
      int k4 = u >> 7, row = u & 127;
      GLOAD_LDS16(key + (size_t)(r0 + row) * Hdim + kc + k4 * 4, AsQ + u * 4);
    }
#pragma unroll
    for (int it = 0; it < 2; ++it) {
      int u = it * 256 + tid;
      GLOAD_LDS16(ubt + ((size_t)nt * 16384 + (kc >> 3) * 128 + u) * 8, Bs + u * 8);
    }
    __syncthreads();

    bf16x8 bfr[4];
#pragma unroll
    for (int j = 0; j < 4; ++j)
      bfr[j] = *(const bf16x8*)&Bs[(quad * 128 + wn + j * 16 + l16) * 8];

    bf16x8 afr[4];
#pragma unroll
    for (int i = 0; i < 4; ++i) {
      int ml = wm + i * 16 + l16;
      float4 f0 = *(const float4*)&AsQ[((quad * 2) * 128 + ml) * 4];
      float4 f1 = *(const float4*)&AsQ[((quad * 2 + 1) * 128 + ml) * 4];
      bf16x8 a;
      a[0] = (__bf16)f0.x; a[1] = (__bf16)f0.y; a[2] = (__bf16)f0.z; a[3] = (__bf16)f0.w;
      a[4] = (__bf16)f1.x; a[5] = (__bf16)f1.y; a[6] = (__bf16)f1.z; a[7] = (__bf16)f1.w;
      afr[i] = a;
    }

#pragma unroll
    for (int i = 0; i < 4; ++i)
#pragma unroll
      for (int j = 0; j < 4; ++j)
        acc[i][j] = __builtin_amdgcn_mfma_f32_16x16x32_bf16(afr[i], bfr[j], acc[i][j], 0, 0, 0);

    __syncthreads();
  }

#pragma unroll
  for (int it = 0; it < 16; ++it) {
    int u = it * 256 + tid;
    AsQ[u] = qc[(u >> 7) * Hdim + n0 + (u & 127)];
  }
  __syncthreads();

  float vav[4];
#pragma unroll
  for (int j = 0; j < 4; ++j) vav[j] = va[n0 + wn + j * 16 + l16];

#pragma unroll
  for (int i = 0; i < 4; ++i) {
#pragma unroll
    for (int rg = 0; rg < 4; ++rg) {
      int b = (i & 1) * 16 + quad * 4 + rg;
      float sum = 0.f;
#pragma unroll
      for (int j = 0; j < 4; ++j) {
        float v = acc[i][j][rg] + AsQ[b * 128 + wn + j * 16 + l16];
        v = fminf(fmaxf(v, -15.f), 15.f);
        float e = __expf(2.f * v);
        sum += (e - 1.f) * __builtin_amdgcn_rcpf(e + 1.f) * vav[j];
      }
#pragma unroll
      for (int off = 1; off < 16; off <<= 1)
        sum += __shfl_xor(sum, off, 64);
      if (l16 == 0)
        red[(wm + i * 16 + quad * 4 + rg) * 2 + (w >> 1)] = sum;
    }
  }
  __syncthreads();
  if (tid < 128) {
    int row = r0 + tid;
    int bb = row & 31, ss = row >> 5;
    part[((size_t)bb * Sdim + ss) * 8 + nt] = red[tid * 2] + red[tid * 2 + 1];
  }
}

// ---------------------------------------------------------------------------
// part layout: [b][s][8 nt-partials]; block b reads 64 KiB fully coalesced.
__global__ __launch_bounds__(256) void softmax_kernel(const float* __restrict__ part,
                                                      float* __restrict__ dout) {
  int b = blockIdx.x, t = threadIdx.x;
  int w = t >> 6, lane = t & 63;
  __shared__ float red1[4], red2[4];
  float sc[8];
  float m = -1e30f;
#pragma unroll
  for (int c = 0; c < 8; ++c) {
    int s = c * 256 + t;
    const float4* p = (const float4*)&part[((size_t)b * Sdim + s) * 8];
    float4 p0 = p[0], p1 = p[1];
    float v = ((p0.x + p0.y) + (p0.z + p0.w)) + ((p1.x + p1.y) + (p1.z + p1.w));
    sc[c] = v;
    m = fmaxf(m, v);
  }
#pragma unroll
  for (int off = 1; off < 64; off <<= 1) m = fmaxf(m, __shfl_xor(m, off, 64));
  if (lane == 0) red1[w] = m;
  __syncthreads();
  m = fmaxf(fmaxf(red1[0], red1[1]), fmaxf(red1[2], red1[3]));
  float sum = 0.f;
#pragma unroll
  for (int c = 0; c < 8; ++c) { sc[c] = __expf(sc[c] - m); sum += sc[c]; }
#pragma unroll
  for (int off = 1; off < 64; off <<= 1) sum += __shfl_xor(sum, off, 64);
  if (lane == 0) red2[w] = sum;
  __syncthreads();
  float inv = 1.f / (red2[0] + red2[1] + red2[2] + red2[3]);
#pragma unroll
  for (int c = 0; c < 8; ++c)
    dout[32768 + b * 2048 + c * 256 + t] = sc[c] * inv;
}

// ---------------------------------------------------------------------------
__global__ __launch_bounds__(256) void ctx_part_kernel(const float* __restrict__ key,
                                                       const float* __restrict__ dout,
                                                       float* __restrict__ cpart) {
  int sc = blockIdx.x;
  int b  = blockIdx.y;
  int t  = threadIdx.x;
  float4 acc = make_float4(0.f, 0.f, 0.f, 0.f);
  int s0 = sc * 64;
#pragma unroll 8
  for (int s = s0; s < s0 + 64; ++s) {
    float wgt = dout[32768 + b * 2048 + s];
    float4 k4 = *(const float4*)&key[((size_t)(s * 32 + b) << 10) + t * 4];
    acc.x = fmaf(wgt, k4.x, acc.x);
    acc.y = fmaf(wgt, k4.y, acc.y);
    acc.z = fmaf(wgt, k4.z, acc.z);
    acc.w = fmaf(wgt, k4.w, acc.w);
  }
  *(float4*)&cpart[((size_t)(sc * 32 + b) << 10) + t * 4] = acc;
}

__global__ __launch_bounds__(256) void ctx_reduce_kernel(const float* __restrict__ cpart,
                                                         float* __restrict__ dout) {
  int o = blockIdx.x * 256 + threadIdx.x;
  int b = o >> 10, h = o & 1023;
  float s = 0.f;
#pragma unroll
  for (int sc = 0; sc < 32; ++sc)
    s += cpart[((size_t)(sc * 32 + b) << 10) + h];
  dout[o] = s;
}

// ---------------------------------------------------------------------------
extern "C" void kernel_launch(void* const* d_in, const int* in_sizes, int n_in,
                              void* d_out, int out_size, void* d_ws, size_t ws_size,
                              hipStream_t stream) {
  const float* q   = (const float*)d_in[0];
  const float* key = (const float*)d_in[1];
  const float* Waw = (const float*)d_in[2];
  const float* Wab = (const float*)d_in[3];
  const float* Uaw = (const float*)d_in[4];
  const float* Uab = (const float*)d_in[5];
  const float* vaw = (const float*)d_in[6];
  float* out = (float*)d_out;  // [0,32768): context ; [32768,98304): weights

  char* ws = (char*)d_ws;
  float*  qc    = (float*)(ws);                                 // 128 KiB
  __bf16* ubt   = (__bf16*)(ws + 131072);                       // 2 MiB
  float*  part  = (float*)(ws + 131072 + 2097152);              // 2 MiB
  float*  cpart = (float*)(ws + 131072 + 2097152 + 2097152);    // 4 MiB
  __bf16* bkey  = (__bf16*)(ws + 131072 + 2097152 + 2097152 + 4194304);  // 128 MiB
  const size_t need = 131072ull + 2097152 + 2097152 + 4194304 + 134217728;

  convert_ua_kernel<<<512, 256, 0, stream>>>(Uaw, ubt);
  qc_kernel<<<dim3(4, 32), 256, 0, stream>>>(q, Waw, Wab, Uab, qc);
  if (ws_size >= need) {
    convert_key_kernel<<<32768, 256, 0, stream>>>(key, bkey);
    gemm_scores_bf16_kernel<<<4096, 256, 0, stream>>>(bkey, ubt, qc, vaw, part);
  } else {
    gemm_scores_kernel<<<4096, 256, 0, stream>>>(key, ubt, qc, vaw, part);
  }
  softmax_kernel<<<32, 256, 0, stream>>>(part, out);
  ctx_part_kernel<<<dim3(32, 32), 256, 0, stream>>>(key, out, cpart);
  ctx_reduce_kernel<<<128, 256, 0, stream>>>(cpart, out);
}

// Round 4
// 674.028 us; speedup vs baseline: 1.2744x; 1.0113x over previous
//
#include <hip/hip_runtime.h>

#define Hdim 1024
#define Bdim 32
#define Sdim 2048

typedef __attribute__((ext_vector_type(8))) __bf16 bf16x8;
typedef __attribute__((ext_vector_type(4))) __bf16 bf16x4;
typedef __attribute__((ext_vector_type(4))) float f32x4;

#define GLOAD_LDS16(gp, lp)                                                              \
  __builtin_amdgcn_global_load_lds(                                                     \
      (const __attribute__((address_space(1))) unsigned int*)(gp),                      \
      (__attribute__((address_space(3))) unsigned int*)(lp), 16, 0, 0)

// ---------------------------------------------------------------------------
// key (S*B x H fp32, row-major) -> bf16, same layout. Block-strided so lanes
// read/write consecutive addresses (fully coalesced both sides).
__global__ __launch_bounds__(256) void convert_key_kernel(const float* __restrict__ key,
                                                          __bf16* __restrict__ bkey) {
  size_t base = (size_t)blockIdx.x * 512 + threadIdx.x;  // float4-unit index
  const float4* src = (const float4*)key;
  float4 f0 = src[base];
  float4 f1 = src[base + 256];
  bf16x4 a, b;
  a[0] = (__bf16)f0.x; a[1] = (__bf16)f0.y; a[2] = (__bf16)f0.z; a[3] = (__bf16)f0.w;
  b[0] = (__bf16)f1.x; b[1] = (__bf16)f1.y; b[2] = (__bf16)f1.z; b[3] = (__bf16)f1.w;
  bf16x4* dst = (bf16x4*)bkey;
  dst[base] = a;
  dst[base + 256] = b;
}

// ---------------------------------------------------------------------------
// Ua (H x H fp32, row-major k-major) -> bf16 in [ntile][k8][n][8] order so the
// GEMM's B staging is fully contiguous per K-chunk (8 KiB per chunk per ntile).
__global__ __launch_bounds__(256) void convert_ua_kernel(const float* __restrict__ Ua,
                                                         __bf16* __restrict__ ubt) {
  int du = blockIdx.x * 256 + threadIdx.x;  // 0..131071 (16B units)
  int n  = du & 127;
  int k8 = (du >> 7) & 127;
  int nt = du >> 14;
  int ng = nt * 128 + n;
  bf16x8 t;
#pragma unroll
  for (int j = 0; j < 8; ++j)
    t[j] = (__bf16)Ua[(k8 * 8 + j) * Hdim + ng];
  *(bf16x8*)(ubt + (size_t)du * 8) = t;
}

// ---------------------------------------------------------------------------
// qc[b,h] = query[b] @ Wa_w + Wa_b + Ua_b   (fp32, tiny: 67 MFLOP)
__global__ __launch_bounds__(256) void qc_kernel(const float* __restrict__ q,
                                                 const float* __restrict__ Wa,
                                                 const float* __restrict__ Wab,
                                                 const float* __restrict__ Uab,
                                                 float* __restrict__ qc) {
  int b = blockIdx.y;
  int h = blockIdx.x * 256 + threadIdx.x;
  float acc = Wab[h] + Uab[h];
  const float* qr = q + b * Hdim;
#pragma unroll 16
  for (int i = 0; i < Hdim; ++i)
    acc = fmaf(qr[i], Wa[i * Hdim + h], acc);
  qc[b * Hdim + h] = acc;
}

// ---------------------------------------------------------------------------
// Fused score GEMM, bf16 A path. 128x128 tile, BK=32, double-buffered LDS,
// T4 counted-vmcnt schedule: per K-step {prefetch(next) -> s_waitcnt vmcnt(4)
// (waits ONLY the current tile's 4 loads, issued one full iteration ago) ->
// s_barrier -> ds_read+MFMA -> s_barrier}. vmcnt never drains to 0 in-loop,
// so prefetch latency hides under compute (m218: counted-vs-drain0 +38-73%).
// part is written TRANSPOSED: part[b][s][nt] so softmax reads coalesced.
#define COMPUTE_TILE(ASPTR)                                                        \
  {                                                                                \
    const __bf16* As_ = (ASPTR);                                                   \
    const __bf16* Bs_ = (ASPTR) + 4096;                                            \
    bf16x8 afr[4], bfr[4];                                                         \
    _Pragma("unroll") for (int i_ = 0; i_ < 4; ++i_)                               \
      afr[i_] = *(const bf16x8*)&As_[(quad * 128 + wm + i_ * 16 + l16) * 8];       \
    _Pragma("unroll") for (int j_ = 0; j_ < 4; ++j_)                               \
      bfr[j_] = *(const bf16x8*)&Bs_[(quad * 128 + wn + j_ * 16 + l16) * 8];       \
    _Pragma("unroll") for (int i_ = 0; i_ < 4; ++i_)                               \
      _Pragma("unroll") for (int j_ = 0; j_ < 4; ++j_)                             \
        acc[i_][j_] = __builtin_amdgcn_mfma_f32_16x16x32_bf16(afr[i_], bfr[j_],    \
                                                              acc[i_][j_], 0, 0, 0); \
  }

__global__ __launch_bounds__(256, 4) void gemm_scores_bf16_kernel(const __bf16* __restrict__ bkey,
                                                                  const __bf16* __restrict__ ubt,
                                                                  const float* __restrict__ qc,
                                                                  const float* __restrict__ va,
                                                                  float* __restrict__ part) {
  // [buf][0..4095] = A tile ([k8][row][8]), [buf][4096..8191] = B tile ([k8][n][8])
  __shared__ __align__(16) __bf16 AB[2][8192];  // 32 KiB; epilogue reuses AB[0] as float[4096]
  __shared__ float red[256];

  const int tid  = threadIdx.x;
  const int w    = tid >> 6;
  const int lane = tid & 63;
  const int quad = lane >> 4;
  const int l16  = lane & 15;

  const int l   = blockIdx.x;
  const int xcd = l & 7;
  const int i2  = l >> 3;
  const int mt  = xcd * 64 + (i2 >> 3);  // 0..511  (same XCD for all 8 nt of one mt)
  const int nt  = i2 & 7;                // 0..7

  const int r0 = mt * 128;
  const int n0 = nt * 128;
  const int wm = (w & 1) * 64;
  const int wn = (w >> 1) * 64;

  // staging source pointers (advance per K-step)
  const __bf16* aSrc = bkey + (size_t)(r0 + (tid & 127)) * Hdim + (tid >> 7) * 8;
  const __bf16* bSrc = ubt + ((size_t)nt * 16384 + tid) * 8;

  f32x4 acc[4][4] = {};

  // ---- prologue: stage tile 0 into buf 0 (4 loads in flight)
  GLOAD_LDS16(aSrc,        &AB[0][tid * 8]);
  GLOAD_LDS16(aSrc + 16,   &AB[0][(tid + 256) * 8]);
  GLOAD_LDS16(bSrc,        &AB[0][4096 + tid * 8]);
  GLOAD_LDS16(bSrc + 2048, &AB[0][4096 + (tid + 256) * 8]);
  aSrc += 32;
  bSrc += 4096;

  int cur = 0;
#pragma unroll 1
  for (int it = 0; it < 31; ++it) {
    // prefetch tile it+1 into buf cur^1 (stays in flight across both barriers)
    __bf16* nb = AB[cur ^ 1];
    GLOAD_LDS16(aSrc,        nb + tid * 8);
    GLOAD_LDS16(aSrc + 16,   nb + (tid + 256) * 8);
    GLOAD_LDS16(bSrc,        nb + 4096 + tid * 8);
    GLOAD_LDS16(bSrc + 2048, nb + 4096 + (tid + 256) * 8);
    aSrc += 32;
    bSrc += 4096;
    // wait only the OLDEST 4 (tile `it`, issued one iteration ago)
    asm volatile("s_waitcnt vmcnt(4)" ::: "memory");
    __builtin_amdgcn_sched_barrier(0);
    __builtin_amdgcn_s_barrier();           // everyone's tile-`it` loads landed
    __builtin_amdgcn_sched_barrier(0);
    COMPUTE_TILE(AB[cur]);
    __builtin_amdgcn_s_barrier();           // everyone's ds_reads of buf cur retired
    cur ^= 1;
  }
  // final K-step: nothing left to prefetch -> full drain is correct here
  asm volatile("s_waitcnt vmcnt(0)" ::: "memory");
  __builtin_amdgcn_sched_barrier(0);
  __builtin_amdgcn_s_barrier();
  __builtin_amdgcn_sched_barrier(0);
  COMPUTE_TILE(AB[cur]);
  __builtin_amdgcn_s_barrier();

  // stage qc tile (32 b-rows x 128 n-cols) into LDS (reuse AB[0] as float[4096])
  float* qcs = (float*)AB[0];
#pragma unroll
  for (int it = 0; it < 16; ++it) {
    int u = it * 256 + tid;
    qcs[u] = qc[(u >> 7) * Hdim + n0 + (u & 127)];
  }
  __syncthreads();

  float vav[4];
#pragma unroll
  for (int j = 0; j < 4; ++j) vav[j] = va[n0 + wn + j * 16 + l16];

  // C/D layout (m89): col = lane&15 (n), row = quad*4 + reg (m)
#pragma unroll
  for (int i = 0; i < 4; ++i) {
#pragma unroll
    for (int rg = 0; rg < 4; ++rg) {
      int b = (i & 1) * 16 + quad * 4 + rg;
      float sum = 0.f;
#pragma unroll
      for (int j = 0; j < 4; ++j) {
        float v = acc[i][j][rg] + qcs[b * 128 + wn + j * 16 + l16];
        v = fminf(fmaxf(v, -15.f), 15.f);
        float e = __expf(2.f * v);
        sum += (e - 1.f) * __builtin_amdgcn_rcpf(e + 1.f) * vav[j];
      }
#pragma unroll
      for (int off = 1; off < 16; off <<= 1)
        sum += __shfl_xor(sum, off, 64);
      if (l16 == 0)
        red[(wm + i * 16 + quad * 4 + rg) * 2 + (w >> 1)] = sum;
    }
  }
  __syncthreads();
  if (tid < 128) {
    int row = r0 + tid;              // row = s*32 + b
    int bb = row & 31, ss = row >> 5;
    part[((size_t)bb * Sdim + ss) * 8 + nt] = red[tid * 2] + red[tid * 2 + 1];
  }
}

// ---------------------------------------------------------------------------
// Fallback fp32-A GEMM (known-good) in case ws can't hold bkey.
__global__ __launch_bounds__(256) void gemm_scores_kernel(const float* __restrict__ key,
                                                          const __bf16* __restrict__ ubt,
                                                          const float* __restrict__ qc,
                                                          const float* __restrict__ va,
                                                          float* __restrict__ part) {
  __shared__ __align__(16) float AsQ[4096];
  __shared__ __align__(16) __bf16 Bs[4096];
  __shared__ float red[256];

  const int tid  = threadIdx.x;
  const int w    = tid >> 6;
  const int lane = tid & 63;
  const int quad = lane >> 4;
  const int l16  = lane & 15;
  const int l   = blockIdx.x;
  const int xcd = l & 7;
  const int i2  = l >> 3;
  const int mt  = xcd * 64 + (i2 >> 3);
  const int nt  = i2 & 7;
  const int r0 = mt * 128;
  const int n0 = nt * 128;
  const int wm = (w & 1) * 64;
  const int wn = (w >> 1) * 64;

  f32x4 acc[4][4] = {};

  for (int kc = 0; kc < Hdim; kc += 32) {
#pragma unroll
    for (int it = 0; it < 4; ++it) {
      int u  = it * 256 + tid;
      int k4 = u >> 7, row = u & 127;
      GLOAD_LDS16(key + (size_t)(r0 + row) * Hdim + kc + k4 * 4, AsQ + u * 4);
    }
#pragma unroll
    for (int it = 0; it < 2; ++it) {
      int u = it * 256 + tid;
      GLOAD_LDS16(ubt + ((size_t)nt * 16384 + (kc >> 3) * 128 + u) * 8, Bs + u * 8);
    }
    __syncthreads();

    bf16x8 bfr[4];
#pragma unroll
    for (int j = 0; j < 4; ++j)
      bfr[j] = *(const bf16x8*)&Bs[(quad * 128 + wn + j * 16 + l16) * 8];

    bf16x8 afr[4];
#pragma unroll
    for (int i = 0; i < 4; ++i) {
      int ml = wm + i * 16 + l16;
      float4 f0 = *(const float4*)&AsQ[((quad * 2) * 128 + ml) * 4];
      float4 f1 = *(const float4*)&AsQ[((quad * 2 + 1) * 128 + ml) * 4];
      bf16x8 a;
      a[0] = (__bf16)f0.x; a[1] = (__bf16)f0.y; a[2] = (__bf16)f0.z; a[3] = (__bf16)f0.w;
      a[4] = (__bf16)f1.x; a[5] = (__bf16)f1.y; a[6] = (__bf16)f1.z; a[7] = (__bf16)f1.w;
      afr[i] = a;
    }

#pragma unroll
    for (int i = 0; i < 4; ++i)
#pragma unroll
      for (int j = 0; j < 4; ++j)
        acc[i][j] = __builtin_amdgcn_mfma_f32_16x16x32_bf16(afr[i], bfr[j], acc[i][j], 0, 0, 0);

    __syncthreads();
  }

#pragma unroll
  for (int it = 0; it < 16; ++it) {
    int u = it * 256 + tid;
    AsQ[u] = qc[(u >> 7) * Hdim + n0 + (u & 127)];
  }
  __syncthreads();

  float vav[4];
#pragma unroll
  for (int j = 0; j < 4; ++j) vav[j] = va[n0 + wn + j * 16 + l16];

#pragma unroll
  for (int i = 0; i < 4; ++i) {
#pragma unroll
    for (int rg = 0; rg < 4; ++rg) {
      int b = (i & 1) * 16 + quad * 4 + rg;
      float sum = 0.f;
#pragma unroll
      for (int j = 0; j < 4; ++j) {
        float v = acc[i][j][rg] + AsQ[b * 128 + wn + j * 16 + l16];
        v = fminf(fmaxf(v, -15.f), 15.f);
        float e = __expf(2.f * v);
        sum += (e - 1.f) * __builtin_amdgcn_rcpf(e + 1.f) * vav[j];
      }
#pragma unroll
      for (int off = 1; off < 16; off <<= 1)
        sum += __shfl_xor(sum, off, 64);
      if (l16 == 0)
        red[(wm + i * 16 + quad * 4 + rg) * 2 + (w >> 1)] = sum;
    }
  }
  __syncthreads();
  if (tid < 128) {
    int row = r0 + tid;
    int bb = row & 31, ss = row >> 5;
    part[((size_t)bb * Sdim + ss) * 8 + nt] = red[tid * 2] + red[tid * 2 + 1];
  }
}

// ---------------------------------------------------------------------------
// part layout: [b][s][8 nt-partials]; block b reads 64 KiB fully coalesced.
__global__ __launch_bounds__(256) void softmax_kernel(const float* __restrict__ part,
                                                      float* __restrict__ dout) {
  int b = blockIdx.x, t = threadIdx.x;
  int w = t >> 6, lane = t & 63;
  __shared__ float red1[4], red2[4];
  float sc[8];
  float m = -1e30f;
#pragma unroll
  for (int c = 0; c < 8; ++c) {
    int s = c * 256 + t;
    const float4* p = (const float4*)&part[((size_t)b * Sdim + s) * 8];
    float4 p0 = p[0], p1 = p[1];
    float v = ((p0.x + p0.y) + (p0.z + p0.w)) + ((p1.x + p1.y) + (p1.z + p1.w));
    sc[c] = v;
    m = fmaxf(m, v);
  }
#pragma unroll
  for (int off = 1; off < 64; off <<= 1) m = fmaxf(m, __shfl_xor(m, off, 64));
  if (lane == 0) red1[w] = m;
  __syncthreads();
  m = fmaxf(fmaxf(red1[0], red1[1]), fmaxf(red1[2], red1[3]));
  float sum = 0.f;
#pragma unroll
  for (int c = 0; c < 8; ++c) { sc[c] = __expf(sc[c] - m); sum += sc[c]; }
#pragma unroll
  for (int off = 1; off < 64; off <<= 1) sum += __shfl_xor(sum, off, 64);
  if (lane == 0) red2[w] = sum;
  __syncthreads();
  float inv = 1.f / (red2[0] + red2[1] + red2[2] + red2[3]);
#pragma unroll
  for (int c = 0; c < 8; ++c)
    dout[32768 + b * 2048 + c * 256 + t] = sc[c] * inv;
}

// ---------------------------------------------------------------------------
__global__ __launch_bounds__(256) void ctx_part_kernel(const float* __restrict__ key,
                                                       const float* __restrict__ dout,
                                                       float* __restrict__ cpart) {
  int sc = blockIdx.x;
  int b  = blockIdx.y;
  int t  = threadIdx.x;
  float4 acc = make_float4(0.f, 0.f, 0.f, 0.f);
  int s0 = sc * 64;
#pragma unroll 8
  for (int s = s0; s < s0 + 64; ++s) {
    float wgt = dout[32768 + b * 2048 + s];
    float4 k4 = *(const float4*)&key[((size_t)(s * 32 + b) << 10) + t * 4];
    acc.x = fmaf(wgt, k4.x, acc.x);
    acc.y = fmaf(wgt, k4.y, acc.y);
    acc.z = fmaf(wgt, k4.z, acc.z);
    acc.w = fmaf(wgt, k4.w, acc.w);
  }
  *(float4*)&cpart[((size_t)(sc * 32 + b) << 10) + t * 4] = acc;
}

__global__ __launch_bounds__(256) void ctx_reduce_kernel(const float* __restrict__ cpart,
                                                         float* __restrict__ dout) {
  int o = blockIdx.x * 256 + threadIdx.x;
  int b = o >> 10, h = o & 1023;
  float s = 0.f;
#pragma unroll
  for (int sc = 0; sc < 32; ++sc)
    s += cpart[((size_t)(sc * 32 + b) << 10) + h];
  dout[o] = s;
}

// ---------------------------------------------------------------------------
extern "C" void kernel_launch(void* const* d_in, const int* in_sizes, int n_in,
                              void* d_out, int out_size, void* d_ws, size_t ws_size,
                              hipStream_t stream) {
  const float* q   = (const float*)d_in[0];
  const float* key = (const float*)d_in[1];
  const float* Waw = (const float*)d_in[2];
  const float* Wab = (const float*)d_in[3];
  const float* Uaw = (const float*)d_in[4];
  const float* Uab = (const float*)d_in[5];
  const float* vaw = (const float*)d_in[6];
  float* out = (float*)d_out;  // [0,32768): context ; [32768,98304): weights

  char* ws = (char*)d_ws;
  float*  qc    = (float*)(ws);                                 // 128 KiB
  __bf16* ubt   = (__bf16*)(ws + 131072);                       // 2 MiB
  float*  part  = (float*)(ws + 131072 + 2097152);              // 2 MiB
  float*  cpart = (float*)(ws + 131072 + 2097152 + 2097152);    // 4 MiB
  __bf16* bkey  = (__bf16*)(ws + 131072 + 2097152 + 2097152 + 4194304);  // 128 MiB
  const size_t need = 131072ull + 2097152 + 2097152 + 4194304 + 134217728;

  convert_ua_kernel<<<512, 256, 0, stream>>>(Uaw, ubt);
  qc_kernel<<<dim3(4, 32), 256, 0, stream>>>(q, Waw, Wab, Uab, qc);
  if (ws_size >= need) {
    convert_key_kernel<<<32768, 256, 0, stream>>>(key, bkey);
    gemm_scores_bf16_kernel<<<4096, 256, 0, stream>>>(bkey, ubt, qc, vaw, part);
  } else {
    gemm_scores_kernel<<<4096, 256, 0, stream>>>(key, ubt, qc, vaw, part);
  }
  softmax_kernel<<<32, 256, 0, stream>>>(part, out);
  ctx_part_kernel<<<dim3(32, 32), 256, 0, stream>>>(key, out, cpart);
  ctx_reduce_kernel<<<128, 256, 0, stream>>>(cpart, out);
}

// Round 5
// 661.361 us; speedup vs baseline: 1.2988x; 1.0192x over previous
//
#include <hip/hip_runtime.h>

#define Hdim 1024
#define Bdim 32
#define Sdim 2048

typedef __attribute__((ext_vector_type(8))) __bf16 bf16x8;
typedef __attribute__((ext_vector_type(4))) __bf16 bf16x4;
typedef __attribute__((ext_vector_type(4))) float f32x4;

#define GLOAD_LDS16(gp, lp)                                                              \
  __builtin_amdgcn_global_load_lds(                                                     \
      (const __attribute__((address_space(1))) unsigned int*)(gp),                      \
      (__attribute__((address_space(3))) unsigned int*)(lp), 16, 0, 0)

#define VMC(n) asm volatile("s_waitcnt vmcnt(" #n ")" ::: "memory")

// ---------------------------------------------------------------------------
// key (S*B x H fp32, row-major) -> bf16, same layout. Fully coalesced.
__global__ __launch_bounds__(256) void convert_key_kernel(const float* __restrict__ key,
                                                          __bf16* __restrict__ bkey) {
  size_t base = (size_t)blockIdx.x * 512 + threadIdx.x;  // float4-unit index
  const float4* src = (const float4*)key;
  float4 f0 = src[base];
  float4 f1 = src[base + 256];
  bf16x4 a, b;
  a[0] = (__bf16)f0.x; a[1] = (__bf16)f0.y; a[2] = (__bf16)f0.z; a[3] = (__bf16)f0.w;
  b[0] = (__bf16)f1.x; b[1] = (__bf16)f1.y; b[2] = (__bf16)f1.z; b[3] = (__bf16)f1.w;
  bf16x4* dst = (bf16x4*)bkey;
  dst[base] = a;
  dst[base + 256] = b;
}

// ---------------------------------------------------------------------------
// Ua (H x H fp32, k-major) -> bf16 in [nt:4][k8:128][n:256][8] order:
// the 256-wide N-panel for one gemm block is a single fully-contiguous
// stream per K-tile (16 KiB), so B staging is perfectly sequential.
__global__ __launch_bounds__(256) void convert_ua_kernel(const float* __restrict__ Ua,
                                                         __bf16* __restrict__ ubt) {
  int du = blockIdx.x * 256 + threadIdx.x;  // 0..131071 (16B units)
  int n  = du & 255;
  int k8 = (du >> 8) & 127;
  int nt = du >> 15;
  int ng = nt * 256 + n;
  bf16x8 t;
#pragma unroll
  for (int j = 0; j < 8; ++j)
    t[j] = (__bf16)Ua[(k8 * 8 + j) * Hdim + ng];
  *(bf16x8*)(ubt + (size_t)du * 8) = t;
}

// ---------------------------------------------------------------------------
// qc[b,h] = query[b] @ Wa_w + Wa_b + Ua_b
__global__ __launch_bounds__(256) void qc_kernel(const float* __restrict__ q,
                                                 const float* __restrict__ Wa,
                                                 const float* __restrict__ Wab,
                                                 const float* __restrict__ Uab,
                                                 float* __restrict__ qc) {
  int b = blockIdx.y;
  int h = blockIdx.x * 256 + threadIdx.x;
  float acc = Wab[h] + Uab[h];
  const float* qr = q + b * Hdim;
#pragma unroll 16
  for (int i = 0; i < Hdim; ++i)
    acc = fmaf(qr[i], Wa[i * Hdim + h], acc);
  qc[b * Hdim + h] = acc;
}

// ---------------------------------------------------------------------------
// Fused score GEMM: 256x256 tile, BK=64, 8 waves (2M x 4N, 128x64 per wave),
// double-buffered 128 KiB LDS, 4-phase-per-K-tile interleave (T3) with
// counted vmcnt (T4) and setprio around MFMA clusters (T5).
// Per tile, stage issue order: A-kk0(2), A-kk1(2), B-kk0(2), B-kk1(2).
// vmcnt(4) at end of phase1 covers this tile's B-kk1 before phase2 reads it;
// vmcnt(2) at end of phase3 covers next tile's A + B-kk0 before its phase0.
// LDS layout [k8][row][8] (k-major): ds_read addresses are lane-consecutive
// 16B -> conflict-free without swizzle (R4-verified layout).
#define PHASE(KK, MH, VMW, ...)                                                        \
  {                                                                                    \
    if ((MH) == 0) {                                                                   \
      _Pragma("unroll") for (int j_ = 0; j_ < 4; ++j_)                                 \
        bfr[j_] = *(const bf16x8*)&Bc[(((KK) * 4 + quad) * 256 + wcol + j_ * 16 + l16) * 8]; \
    }                                                                                  \
    _Pragma("unroll") for (int i_ = 0; i_ < 4; ++i_)                                   \
      afr[i_] = *(const bf16x8*)&Ac[(((KK) * 4 + quad) * 256 + wrow + (MH) * 64 + i_ * 16 + l16) * 8]; \
    __VA_ARGS__;                                                                       \
    __builtin_amdgcn_s_barrier();                                                      \
    asm volatile("s_waitcnt lgkmcnt(0)" ::: "memory");                                 \
    __builtin_amdgcn_sched_barrier(0);                                                 \
    __builtin_amdgcn_s_setprio(1);                                                     \
    _Pragma("unroll") for (int i_ = 0; i_ < 4; ++i_)                                   \
      _Pragma("unroll") for (int j_ = 0; j_ < 4; ++j_)                                 \
        acc[(MH) * 4 + i_][j_] = __builtin_amdgcn_mfma_f32_16x16x32_bf16(              \
            afr[i_], bfr[j_], acc[(MH) * 4 + i_][j_], 0, 0, 0);                        \
    __builtin_amdgcn_s_setprio(0);                                                     \
    VMW;                                                                               \
    __builtin_amdgcn_s_barrier();                                                      \
  }

__global__ __launch_bounds__(512, 2) void gemm_scores_bf16_kernel(const __bf16* __restrict__ bkey,
                                                                  const __bf16* __restrict__ ubt,
                                                                  const float* __restrict__ qc,
                                                                  const float* __restrict__ va,
                                                                  float* __restrict__ part) {
  // LB: [buf d][A: 16384 elems = [k8:8][row:256][8]][B: 16384 = [k8:8][n:256][8]]
  __shared__ __align__(16) __bf16 LB[65536];   // 128 KiB
  __shared__ __align__(16) float red[1024];    // [row_local:256][wn:4]

  const int tid  = threadIdx.x;
  const int w    = tid >> 6;
  const int lane = tid & 63;
  const int quad = lane >> 4;
  const int l16  = lane & 15;

  const int l   = blockIdx.x;            // 1024 blocks = 8 xcd * 128
  const int xcd = l & 7;
  const int i2  = l >> 3;
  const int mt  = xcd * 32 + (i2 >> 2);  // 0..255 (all 4 nt of one mt on same XCD)
  const int nt  = i2 & 3;                // 0..3

  const int r0 = mt * 256;
  const int n0 = nt * 256;
  const int wrow = (w & 1) * 128;        // wave tile: 128 rows x 64 cols
  const int wcol = (w >> 1) * 64;

  // staging source pointers
  const __bf16* aS = bkey + (size_t)(r0 + (tid & 255)) * Hdim + ((tid >> 8) * 8);
  const __bf16* bS = ubt + (size_t)nt * 262144 + (size_t)tid * 8;

  f32x4 acc[8][4] = {};
  bf16x8 afr[4], bfr[4];

  // ---- prologue: stage tile 0 into buf 0, order A0 A1 B0 B1 (2 loads each)
  GLOAD_LDS16(aS,          LB + (size_t)tid * 8);
  GLOAD_LDS16(aS + 16,     LB + (size_t)(tid + 512) * 8);
  GLOAD_LDS16(aS + 32,     LB + (size_t)(tid + 1024) * 8);
  GLOAD_LDS16(aS + 48,     LB + (size_t)(tid + 1536) * 8);
  GLOAD_LDS16(bS,          LB + 16384 + (size_t)tid * 8);
  GLOAD_LDS16(bS + 4096,   LB + 16384 + (size_t)(tid + 512) * 8);
  GLOAD_LDS16(bS + 8192,   LB + 16384 + (size_t)(tid + 1024) * 8);
  GLOAD_LDS16(bS + 12288,  LB + 16384 + (size_t)(tid + 1536) * 8);
  aS += 64;     // -> tile 1
  bS += 16384;
  VMC(2);       // A0,A1,B0 of tile 0 landed (B1 covered by phase-1 vmcnt(4))
  __builtin_amdgcn_s_barrier();
  __builtin_amdgcn_sched_barrier(0);

  int cur = 0;
#pragma unroll 1
  for (int t = 0; t < 15; ++t) {
    const __bf16* Ac = LB + cur * 32768;
    const __bf16* Bc = Ac + 16384;
    __bf16* An = LB + (cur ^ 1) * 32768;
    __bf16* Bn = An + 16384;

    PHASE(0, 0, (void)0,
      GLOAD_LDS16(aS,         An + (size_t)tid * 8);
      GLOAD_LDS16(aS + 16,    An + (size_t)(tid + 512) * 8));
    PHASE(0, 1, VMC(4),       // waits this tile's B-kk1 (oldest pair)
      GLOAD_LDS16(aS + 32,    An + (size_t)(tid + 1024) * 8);
      GLOAD_LDS16(aS + 48,    An + (size_t)(tid + 1536) * 8));
    PHASE(1, 0, (void)0,
      GLOAD_LDS16(bS,         Bn + (size_t)tid * 8);
      GLOAD_LDS16(bS + 4096,  Bn + (size_t)(tid + 512) * 8));
    PHASE(1, 1, VMC(2),       // waits next tile's A0,A1,B0; leaves B1 in flight
      GLOAD_LDS16(bS + 8192,  Bn + (size_t)(tid + 1024) * 8);
      GLOAD_LDS16(bS + 12288, Bn + (size_t)(tid + 1536) * 8));

    aS += 64;
    bS += 16384;
    cur ^= 1;
  }
  // ---- tail tile (t=15): no staging; drain remaining B-kk1 before phase 2
  {
    const __bf16* Ac = LB + cur * 32768;
    const __bf16* Bc = Ac + 16384;
    PHASE(0, 0, (void)0, (void)0);
    PHASE(0, 1, VMC(0), (void)0);
    PHASE(1, 0, (void)0, (void)0);
    PHASE(1, 1, (void)0, (void)0);
  }

  // ---- epilogue: qc tile (32 b-rows x 256 n-cols, 32 KiB) overlays LB
  float* qcs = (float*)LB;
  __syncthreads();
#pragma unroll
  for (int it = 0; it < 16; ++it) {
    int u = it * 512 + tid;
    qcs[u] = qc[(u >> 8) * Hdim + n0 + (u & 255)];
  }
  __syncthreads();

  float vav[4];
#pragma unroll
  for (int j = 0; j < 4; ++j) vav[j] = va[n0 + wcol + j * 16 + l16];

  // C/D layout (m89): col = l16 (n), row = quad*4 + reg (m)
#pragma unroll
  for (int mf = 0; mf < 8; ++mf) {
#pragma unroll
    for (int rg = 0; rg < 4; ++rg) {
      int b = ((mf & 1) * 16) + quad * 4 + rg;   // batch index within 32
      float sum = 0.f;
#pragma unroll
      for (int j = 0; j < 4; ++j) {
        float v = acc[mf][j][rg] + qcs[b * 256 + wcol + j * 16 + l16];
        v = fminf(fmaxf(v, -15.f), 15.f);
        float e = __expf(2.f * v);
        sum += (e - 1.f) * __builtin_amdgcn_rcpf(e + 1.f) * vav[j];
      }
#pragma unroll
      for (int off = 1; off < 16; off <<= 1)
        sum += __shfl_xor(sum, off, 64);
      if (l16 == 0)
        red[(wrow + mf * 16 + quad * 4 + rg) * 4 + (w >> 1)] = sum;
    }
  }
  __syncthreads();
  if (tid < 256) {
    const float4 r4 = *(const float4*)&red[tid * 4];
    int row = r0 + tid;                  // row = s*32 + b
    int bb = row & 31, ss = row >> 5;
    part[((size_t)bb * Sdim + ss) * 4 + nt] = (r4.x + r4.y) + (r4.z + r4.w);
  }
}

// ---------------------------------------------------------------------------
// part layout: [b][s][4 nt-partials]; block b reads 32 KiB fully coalesced.
__global__ __launch_bounds__(256) void softmax_kernel(const float* __restrict__ part,
                                                      float* __restrict__ dout) {
  int b = blockIdx.x, t = threadIdx.x;
  int w = t >> 6, lane = t & 63;
  __shared__ float red1[4], red2[4];
  float sc[8];
  float m = -1e30f;
#pragma unroll
  for (int c = 0; c < 8; ++c) {
    int s = c * 256 + t;
    const float4 p0 = *(const float4*)&part[((size_t)b * Sdim + s) * 4];
    float v = (p0.x + p0.y) + (p0.z + p0.w);
    sc[c] = v;
    m = fmaxf(m, v);
  }
#pragma unroll
  for (int off = 1; off < 64; off <<= 1) m = fmaxf(m, __shfl_xor(m, off, 64));
  if (lane == 0) red1[w] = m;
  __syncthreads();
  m = fmaxf(fmaxf(red1[0], red1[1]), fmaxf(red1[2], red1[3]));
  float sum = 0.f;
#pragma unroll
  for (int c = 0; c < 8; ++c) { sc[c] = __expf(sc[c] - m); sum += sc[c]; }
#pragma unroll
  for (int off = 1; off < 64; off <<= 1) sum += __shfl_xor(sum, off, 64);
  if (lane == 0) red2[w] = sum;
  __syncthreads();
  float inv = 1.f / (red2[0] + red2[1] + red2[2] + red2[3]);
#pragma unroll
  for (int c = 0; c < 8; ++c)
    dout[32768 + b * 2048 + c * 256 + t] = sc[c] * inv;
}

// ---------------------------------------------------------------------------
__global__ __launch_bounds__(256) void ctx_part_kernel(const float* __restrict__ key,
                                                       const float* __restrict__ dout,
                                                       float* __restrict__ cpart) {
  int sc = blockIdx.x;
  int b  = blockIdx.y;
  int t  = threadIdx.x;
  float4 acc = make_float4(0.f, 0.f, 0.f, 0.f);
  int s0 = sc * 64;
#pragma unroll 8
  for (int s = s0; s < s0 + 64; ++s) {
    float wgt = dout[32768 + b * 2048 + s];
    float4 k4 = *(const float4*)&key[((size_t)(s * 32 + b) << 10) + t * 4];
    acc.x = fmaf(wgt, k4.x, acc.x);
    acc.y = fmaf(wgt, k4.y, acc.y);
    acc.z = fmaf(wgt, k4.z, acc.z);
    acc.w = fmaf(wgt, k4.w, acc.w);
  }
  *(float4*)&cpart[((size_t)(sc * 32 + b) << 10) + t * 4] = acc;
}

__global__ __launch_bounds__(256) void ctx_reduce_kernel(const float* __restrict__ cpart,
                                                         float* __restrict__ dout) {
  int o = blockIdx.x * 256 + threadIdx.x;
  int b = o >> 10, h = o & 1023;
  float s = 0.f;
#pragma unroll
  for (int sc = 0; sc < 32; ++sc)
    s += cpart[((size_t)(sc * 32 + b) << 10) + h];
  dout[o] = s;
}

// ---------------------------------------------------------------------------
extern "C" void kernel_launch(void* const* d_in, const int* in_sizes, int n_in,
                              void* d_out, int out_size, void* d_ws, size_t ws_size,
                              hipStream_t stream) {
  const float* q   = (const float*)d_in[0];
  const float* key = (const float*)d_in[1];
  const float* Waw = (const float*)d_in[2];
  const float* Wab = (const float*)d_in[3];
  const float* Uaw = (const float*)d_in[4];
  const float* Uab = (const float*)d_in[5];
  const float* vaw = (const float*)d_in[6];
  float* out = (float*)d_out;  // [0,32768): context ; [32768,98304): weights

  char* ws = (char*)d_ws;
  float*  qc    = (float*)(ws);                                 // 128 KiB
  __bf16* ubt   = (__bf16*)(ws + 131072);                       // 2 MiB
  float*  part  = (float*)(ws + 131072 + 2097152);              // 1 MiB used (2 MiB slot)
  float*  cpart = (float*)(ws + 131072 + 2097152 + 2097152);    // 4 MiB
  __bf16* bkey  = (__bf16*)(ws + 131072 + 2097152 + 2097152 + 4194304);  // 128 MiB

  convert_ua_kernel<<<512, 256, 0, stream>>>(Uaw, ubt);
  qc_kernel<<<dim3(4, 32), 256, 0, stream>>>(q, Waw, Wab, Uab, qc);
  convert_key_kernel<<<32768, 256, 0, stream>>>(key, bkey);
  gemm_scores_bf16_kernel<<<1024, 512, 0, stream>>>(bkey, ubt, qc, vaw, part);
  softmax_kernel<<<32, 256, 0, stream>>>(part, out);
  ctx_part_kernel<<<dim3(32, 32), 256, 0, stream>>>(key, out, cpart);
  ctx_reduce_kernel<<<128, 256, 0, stream>>>(cpart, out);
}